// Round 8
// baseline (42296.274 us; speedup 1.0000x reference)
//
#include <hip/hip_runtime.h>

typedef short v8s __attribute__((ext_vector_type(8)));
typedef float f32x4 __attribute__((ext_vector_type(4)));
typedef unsigned short u16;
typedef unsigned int u32;

static constexpr int kB = 64;    // batch
static constexpr int kH = 1024;  // hidden
static constexpr int kD = 128;   // input dim
static constexpr int kL = 3;     // layers
static constexpr int NBLK = 128; // proven cooperative grid size
static constexpr int NTHR = 512; // 8 waves -> 8-way K-split
static constexpr int NFLAG = 8192;

__device__ __forceinline__ u16 f2b(float f) {
  union { float f; unsigned u; } v; v.f = f;
  unsigned r = v.u + 0x7fffu + ((v.u >> 16) & 1u);
  return (u16)(r >> 16);
}

__device__ __forceinline__ float sigm(float x) { return 1.f / (1.f + expf(-x)); }

// DEVICE-scope write-through stores (sc1 only): land at LLC, not HBM.
__device__ __forceinline__ void st16(u16* p, u16 v) {
  unsigned d = v;
  asm volatile("global_store_short %0, %1, off sc1" :: "v"(p), "v"(d) : "memory");
}
__device__ __forceinline__ void st32(float* p, float v) {
  asm volatile("global_store_dword %0, %1, off sc1" :: "v"(p), "v"(v) : "memory");
}

struct Params {
  const float *x, *h0, *c0;
  const float *Wi0, *Wh0, *bi0, *bh0;
  const float *Wi1, *Wh1, *bi1, *bh1;
  const float *Wi2, *Wh2, *bi2, *bh2;
  const float *Wfc, *bfc;
  float *out;
  u16 *wb0i, *wb0h, *wb1i, *wb1h, *wb2i, *wb2h, *wbfc;
  u16 *xb, *hA, *hB;
  float *b0, *b1, *b2;
  unsigned *bflags;  // flag line per block at [b*32]; monotone generations
  int P, T;
};

// One-hop all-to-all grid barrier, LLC-resident (agent scope).
// Arrival: drain this wave's sc1 stores (vmcnt), block-sync, thread0 stores
// its own flag line (parallel across blocks, no RMW). Detect: 128 threads
// poll all 128 flags; __syncthreads_and. Exit: ACQUIRE load -> buffer_inv.
__device__ __forceinline__ void gbar(unsigned* flags, unsigned& g, int bid) {
  const unsigned tgt = g + 1u;
  asm volatile("s_waitcnt vmcnt(0)" ::: "memory");
  __syncthreads();
  if (threadIdx.x == 0)
    __hip_atomic_store(flags + bid * 32, tgt, __ATOMIC_RELAXED, __HIP_MEMORY_SCOPE_AGENT);
  {
    const int i = threadIdx.x;
    for (;;) {
      unsigned v = tgt;
      if (i < NBLK)
        v = __hip_atomic_load(flags + i * 32, __ATOMIC_RELAXED, __HIP_MEMORY_SCOPE_AGENT);
      if (__syncthreads_and((int)(v >= tgt))) break;
      __builtin_amdgcn_s_sleep(1);
    }
  }
  (void)__hip_atomic_load(flags, __ATOMIC_ACQUIRE, __HIP_MEMORY_SCOPE_AGENT);
  g = tgt;
}

// ---------------- init: fp32 -> bf16 conversions, bias sums, state init ----
__global__ void init_kernel(Params p) {
  long gid = (long)blockIdx.x * blockDim.x + threadIdx.x;
  long stride = (long)gridDim.x * blockDim.x;
  const long nw0i = 4096L * kD, nwh = 4096L * kH, nfc = (long)kD * kH;
  for (long i = gid; i < nw0i; i += stride) p.wb0i[i] = f2b(p.Wi0[i]);
  for (long i = gid; i < nwh; i += stride) {
    p.wb0h[i] = f2b(p.Wh0[i]);
    p.wb1i[i] = f2b(p.Wi1[i]);
    p.wb1h[i] = f2b(p.Wh1[i]);
    p.wb2i[i] = f2b(p.Wi2[i]);
    p.wb2h[i] = f2b(p.Wh2[i]);
  }
  for (long i = gid; i < nfc; i += stride) p.wbfc[i] = f2b(p.Wfc[i]);
  for (long i = gid; i < 4096; i += stride) {
    p.b0[i] = p.bi0[i] + p.bh0[i];
    p.b1[i] = p.bi1[i] + p.bh1[i];
    p.b2[i] = p.bi2[i] + p.bh2[i];
  }
  for (long i = gid; i < NFLAG; i += stride) p.bflags[i] = 0u;
  long nx = (long)p.P * kB * kD;
  for (long i = gid; i < nx; i += stride) {
    p.xb[i] = f2b(p.x[i]);
    p.out[i] = p.x[i];  // teacher-forced rows are exact copies
  }
  long nh = (long)kL * kB * kH;
  for (long i = gid; i < nh; i += stride) p.hA[i] = f2b(p.h0[i]);
}

// ---------------- persistent RNN: weights live in VGPRs, 8-way K-split ----
// 128 blocks x 512 thr. Block owns 8 hidden units [8b,8b+8) x 4 gates = 32
// gate-rows/layer as TWO n-tiles: tile j = gates {2j,2j+1}; col c -> gate
// 2j+(c>>3), unit c&7. Wave w (0..7) owns 1/8 of K; partials sum via LDS.
// FC is computed redundantly by every block into LDS xin (no 4th barrier).
// MFMA 16x16x32: A row=lane&15(m), k=(lane>>4)*8+j; D col=lane&15, row=kq*4+r.
__global__ void __launch_bounds__(NTHR) rnn_kernel(Params p) {
  const int tid = threadIdx.x, bid = blockIdx.x;
  const int lane = tid & 63, w = tid >> 6;  // 8 waves
  const int colc = lane & 15, kq = lane >> 4;
  const int aoff = kq * 8;
  const int u7 = colc & 7, gh = colc >> 3;
  const long wr0 = (long)gh * kH + bid * 8 + u7;        // gate-rows 0/1 tile
  const long wr1 = (long)(2 + gh) * kH + bid * 8 + u7;  // gate-rows 2/3 tile
  unsigned bg = 0;

  __shared__ float lg[8][64][18];    // layer partials (36.9 KB)
  __shared__ float fcp[8][16][132];  // FC partials    (67.6 KB)
  __shared__ u16 xin[64 * 136];      // FC output / next-step x (17.4 KB)
  __shared__ float bfl[128];         // FC bias

  if (tid < 128) bfl[tid] = p.bfc[tid];

  // ---- one-time weight preload: 42 tiles = 168 regs/wave ----
  const int cnt0 = (w < 4) ? 5 : 4;
  const int off0 = (w < 4) ? w * 5 : 20 + (w - 4) * 4;
  v8s w0[2][5], w1[2][8], w2[2][8];
#pragma unroll
  for (int i = 0; i < 5; ++i)
    if (i < cnt0) {
      int gt = off0 + i;
      if (gt < 4) {
        w0[0][i] = *(const v8s*)(p.wb0i + wr0 * kD + gt * 32 + aoff);
        w0[1][i] = *(const v8s*)(p.wb0i + wr1 * kD + gt * 32 + aoff);
      } else {
        w0[0][i] = *(const v8s*)(p.wb0h + wr0 * kH + (gt - 4) * 32 + aoff);
        w0[1][i] = *(const v8s*)(p.wb0h + wr1 * kH + (gt - 4) * 32 + aoff);
      }
    }
#pragma unroll
  for (int i = 0; i < 8; ++i) {
    int gt = w * 8 + i;
    const u16* s1 = (gt < 32) ? p.wb1i : p.wb1h;
    const u16* s2 = (gt < 32) ? p.wb2i : p.wb2h;
    int k = (gt & 31) * 32 + aoff;
    w1[0][i] = *(const v8s*)(s1 + wr0 * kH + k);
    w1[1][i] = *(const v8s*)(s1 + wr1 * kH + k);
    w2[0][i] = *(const v8s*)(s2 + wr0 * kH + k);
    w2[1][i] = *(const v8s*)(s2 + wr1 * kH + k);
  }

  // ---- per-thread cell state: 1 (batch, unit) cell per layer ----
  const int em = tid >> 3, eu = tid & 7;
  const int ehid = bid * 8 + eu;
  float cst[kL], brg[kL][4];
#pragma unroll
  for (int l = 0; l < kL; ++l)
    cst[l] = p.c0[(long)l * kB * kH + (long)em * kH + ehid];
  {
    const float* bp[3] = {p.b0, p.b1, p.b2};
#pragma unroll
    for (int l = 0; l < 3; ++l)
#pragma unroll
      for (int gg = 0; gg < 4; ++gg) brg[l][gg] = bp[l][gg * kH + ehid];
  }
  __syncthreads();  // bfl visible

  const int T = p.T, P = p.P;
  const f32x4 z4 = {0.f, 0.f, 0.f, 0.f};

  auto epilogue = [&](int l, f32x4(&acc)[2][4], u16* hOut) {
    float pre[4];
#pragma unroll
    for (int mt = 0; mt < 4; ++mt)
#pragma unroll
      for (int r = 0; r < 4; ++r) lg[w][mt * 16 + kq * 4 + r][colc] = acc[0][mt][r];
    __syncthreads();
    {
      float s0 = 0.f, s1 = 0.f;
#pragma unroll
      for (int ww = 0; ww < 8; ++ww) {
        s0 += lg[ww][em][eu];
        s1 += lg[ww][em][8 + eu];
      }
      pre[0] = s0;
      pre[1] = s1;
    }
    __syncthreads();
#pragma unroll
    for (int mt = 0; mt < 4; ++mt)
#pragma unroll
      for (int r = 0; r < 4; ++r) lg[w][mt * 16 + kq * 4 + r][colc] = acc[1][mt][r];
    __syncthreads();
    {
      float s0 = 0.f, s1 = 0.f;
#pragma unroll
      for (int ww = 0; ww < 8; ++ww) {
        s0 += lg[ww][em][eu];
        s1 += lg[ww][em][8 + eu];
      }
      pre[2] = s0;
      pre[3] = s1;
    }
    float iv = pre[0] + brg[l][0], fv = pre[1] + brg[l][1];
    float gv = pre[2] + brg[l][2], ov = pre[3] + brg[l][3];
    float cn = sigm(fv) * cst[l] + sigm(iv) * tanhf(gv);
    cst[l] = cn;
    st16(hOut + (long)em * kH + ehid, f2b(sigm(ov) * tanhf(cn)));
  };

  for (int t = 0; t < T - 1; ++t) {
    const u16* hOld = (t & 1) ? p.hB : p.hA;
    u16* hNew = (t & 1) ? p.hA : p.hB;

    // ===== layer 0 (x-part: global xb during prompt, LDS xin during gen) ====
    {
      f32x4 acc[2][4] = {z4, z4, z4, z4, z4, z4, z4, z4};
#pragma unroll
      for (int i = 0; i < 5; ++i)
        if (i < cnt0) {
          int gt = off0 + i;
          if (gt < 4) {
            int k = gt * 32 + aoff;
#pragma unroll
            for (int mt = 0; mt < 4; ++mt) {
              v8s a;
              if (t < P)
                a = *(const v8s*)(p.xb + (long)t * kB * kD + (long)(mt * 16 + colc) * kD + k);
              else
                a = *(const v8s*)(xin + (mt * 16 + colc) * 136 + k);
              acc[0][mt] = __builtin_amdgcn_mfma_f32_16x16x32_bf16(a, w0[0][i], acc[0][mt], 0, 0, 0);
              acc[1][mt] = __builtin_amdgcn_mfma_f32_16x16x32_bf16(a, w0[1][i], acc[1][mt], 0, 0, 0);
            }
          } else {
            int k = (gt - 4) * 32 + aoff;
#pragma unroll
            for (int mt = 0; mt < 4; ++mt) {
              v8s a = *(const v8s*)(hOld + (long)(mt * 16 + colc) * kH + k);
              acc[0][mt] = __builtin_amdgcn_mfma_f32_16x16x32_bf16(a, w0[0][i], acc[0][mt], 0, 0, 0);
              acc[1][mt] = __builtin_amdgcn_mfma_f32_16x16x32_bf16(a, w0[1][i], acc[1][mt], 0, 0, 0);
            }
          }
        }
      epilogue(0, acc, hNew);
    }
    gbar(p.bflags, bg, bid);

    // ===== layer 1 (x-part = h_l0 new, h-part = h_l1 old) =====
    {
      f32x4 acc[2][4] = {z4, z4, z4, z4, z4, z4, z4, z4};
      const u16* Ax = hNew;
      const u16* Ah = hOld + (long)kB * kH;
#pragma unroll
      for (int i = 0; i < 8; ++i) {
        int gt = w * 8 + i;
        const u16* Ab = (gt < 32) ? Ax : Ah;
        int k = (gt & 31) * 32 + aoff;
#pragma unroll
        for (int mt = 0; mt < 4; ++mt) {
          v8s a = *(const v8s*)(Ab + (long)(mt * 16 + colc) * kH + k);
          acc[0][mt] = __builtin_amdgcn_mfma_f32_16x16x32_bf16(a, w1[0][i], acc[0][mt], 0, 0, 0);
          acc[1][mt] = __builtin_amdgcn_mfma_f32_16x16x32_bf16(a, w1[1][i], acc[1][mt], 0, 0, 0);
        }
      }
      epilogue(1, acc, hNew + (long)kB * kH);
    }
    gbar(p.bflags, bg, bid);

    // ===== layer 2 =====
    {
      f32x4 acc[2][4] = {z4, z4, z4, z4, z4, z4, z4, z4};
      const u16* Ax = hNew + (long)kB * kH;
      const u16* Ah = hOld + 2L * kB * kH;
#pragma unroll
      for (int i = 0; i < 8; ++i) {
        int gt = w * 8 + i;
        const u16* Ab = (gt < 32) ? Ax : Ah;
        int k = (gt & 31) * 32 + aoff;
#pragma unroll
        for (int mt = 0; mt < 4; ++mt) {
          v8s a = *(const v8s*)(Ab + (long)(mt * 16 + colc) * kH + k);
          acc[0][mt] = __builtin_amdgcn_mfma_f32_16x16x32_bf16(a, w2[0][i], acc[0][mt], 0, 0, 0);
          acc[1][mt] = __builtin_amdgcn_mfma_f32_16x16x32_bf16(a, w2[1][i], acc[1][mt], 0, 0, 0);
        }
      }
      epilogue(2, acc, hNew + 2L * kB * kH);
    }
    gbar(p.bflags, bg, bid);

    // ===== FC: every block computes full 64x128 into LDS xin (no barrier) ==
    if (t >= P - 1) {
      const u16* h2 = hNew + 2L * kB * kH;
      const int fmt = w & 3, kh = w >> 2;  // wave = (m-tile, K-half)
      f32x4 fa[8] = {z4, z4, z4, z4, z4, z4, z4, z4};
      const u16* ap = h2 + (long)(fmt * 16 + colc) * kH + kh * 512 + aoff;
      const u16* bp = p.wbfc + (long)colc * kH + kh * 512 + aoff;
#pragma unroll 2
      for (int kt = 0; kt < 16; ++kt) {
        v8s a = *(const v8s*)(ap + kt * 32);
#pragma unroll
        for (int nt = 0; nt < 8; ++nt) {
          v8s b = *(const v8s*)(bp + (long)nt * 16 * kH + kt * 32);
          fa[nt] = __builtin_amdgcn_mfma_f32_16x16x32_bf16(a, b, fa[nt], 0, 0, 0);
        }
      }
#pragma unroll
      for (int nt = 0; nt < 8; ++nt)
#pragma unroll
        for (int r = 0; r < 4; ++r)
          fcp[w][kq * 4 + r][nt * 16 + colc] = fa[nt][r];
      __syncthreads();
      {
        const int rr = tid >> 3, cg = tid & 7;  // batch row, col-group of 16
        const int ms = rr >> 4, mr = rr & 15;
        float* orow = p.out + (long)(t + 1) * (kB * kD) + (long)rr * kD;
        const bool wout = (bid == (rr >> 3));
#pragma unroll
        for (int j = 0; j < 16; j += 2) {
          int col = cg * 16 + j;
          float v0 = fcp[ms][mr][col] + fcp[ms + 4][mr][col] + bfl[col];
          float v1 = fcp[ms][mr][col + 1] + fcp[ms + 4][mr][col + 1] + bfl[col + 1];
          float s0 = sigm(v0), s1 = sigm(v1);
          *(u32*)(xin + rr * 136 + col) = (u32)f2b(s0) | ((u32)f2b(s1) << 16);
          if (wout) {
            st32(orow + col, s0);
            st32(orow + col + 1, s1);
          }
        }
      }
      __syncthreads();  // xin ready for this block's next L0
    }
  }
}

extern "C" void kernel_launch(void* const* d_in, const int* in_sizes, int n_in,
                              void* d_out, int out_size, void* d_ws, size_t ws_size,
                              hipStream_t stream) {
  Params p;
  p.x   = (const float*)d_in[0];
  p.h0  = (const float*)d_in[1];
  p.c0  = (const float*)d_in[2];
  p.Wi0 = (const float*)d_in[3];
  p.Wh0 = (const float*)d_in[4];
  p.bi0 = (const float*)d_in[5];
  p.bh0 = (const float*)d_in[6];
  p.Wi1 = (const float*)d_in[7];
  p.Wh1 = (const float*)d_in[8];
  p.bi1 = (const float*)d_in[9];
  p.bh1 = (const float*)d_in[10];
  p.Wi2 = (const float*)d_in[11];
  p.Wh2 = (const float*)d_in[12];
  p.bi2 = (const float*)d_in[13];
  p.bh2 = (const float*)d_in[14];
  p.Wfc = (const float*)d_in[15];
  p.bfc = (const float*)d_in[16];
  p.out = (float*)d_out;
  p.P = in_sizes[0] / (kB * kD);
  p.T = out_size / (kB * kD);

  char* w = (char*)d_ws;
  auto alloc = [&](size_t bytes) {
    char* r = w;
    w += (bytes + 255) & ~(size_t)255;
    return r;
  };
  p.wb0i = (u16*)alloc(4096L * kD * 2);
  p.wb0h = (u16*)alloc(4096L * kH * 2);
  p.wb1i = (u16*)alloc(4096L * kH * 2);
  p.wb1h = (u16*)alloc(4096L * kH * 2);
  p.wb2i = (u16*)alloc(4096L * kH * 2);
  p.wb2h = (u16*)alloc(4096L * kH * 2);
  p.wbfc = (u16*)alloc((long)kD * kH * 2);
  p.xb   = (u16*)alloc((long)p.P * kB * kD * 2);
  p.hA   = (u16*)alloc((long)kL * kB * kH * 2);
  p.hB   = (u16*)alloc((long)kL * kB * kH * 2);
  p.b0   = (float*)alloc(4096 * 4);
  p.b1   = (float*)alloc(4096 * 4);
  p.b2   = (float*)alloc(4096 * 4);
  p.bflags = (unsigned*)alloc(NFLAG * 4);

  hipLaunchKernelGGL(init_kernel, dim3(512), dim3(256), 0, stream, p);
  void* args[] = { &p };
  hipLaunchCooperativeKernel((const void*)rnn_kernel, dim3(NBLK), dim3(NTHR),
                             args, 0, stream);
}